// Round 7
// baseline (1352.105 us; speedup 1.0000x reference)
//
#include <hip/hip_runtime.h>
#include <stdint.h>

typedef unsigned short u16;
typedef __bf16 bf16x8 __attribute__((ext_vector_type(8)));
typedef float f32x4 __attribute__((ext_vector_type(4)));

#define DEVINL __device__ __forceinline__

DEVINL u16 f2bf(float f) {
  union { float f; unsigned u; } c; c.f = f;
  unsigned u = c.u + 0x7FFFu + ((c.u >> 16) & 1u);
  return (u16)(u >> 16);
}

DEVINL float bf2f(u16 v) {
  union { unsigned u; float f; } c; c.u = (unsigned)v << 16;
  return c.f;
}

// packed fp32x2 -> bf16x2 (HW instruction when available; RNE either way)
DEVINL unsigned pk2bf(float a, float b) {
#if __has_builtin(__builtin_amdgcn_cvt_pk_bf16_f32)
  auto r = __builtin_amdgcn_cvt_pk_bf16_f32(a, b);
  unsigned u;
  __builtin_memcpy(&u, &r, 4);
  return u;
#else
  return (unsigned)f2bf(a) | ((unsigned)f2bf(b) << 16);
#endif
}

DEVINL void gl2lds16(const void* g, void* l) {
  __builtin_amdgcn_global_load_lds(
      (const __attribute__((address_space(1))) unsigned int*)g,
      (__attribute__((address_space(3))) unsigned int*)l, 16, 0, 0);
}

DEVINL void waitlgkm0() { asm volatile("s_waitcnt lgkmcnt(0)" ::: "memory"); }
// raw barrier WITHOUT the __syncthreads vmcnt(0) drain
DEVINL void bar() {
  asm volatile("" ::: "memory");
  __builtin_amdgcn_s_barrier();
  asm volatile("" ::: "memory");
}

// ---------------- fused 4-segment fp32 -> bf16 conversion ----------------
// counts are in units of 8 floats; grid-stride; 32B in / 16B out per thread-iter
__global__ __launch_bounds__(256) void cvt8_kernel(
    const float* __restrict__ s0, u16* __restrict__ d0, int n0,
    const float* __restrict__ s1, u16* __restrict__ d1, int n1,
    const float* __restrict__ s2, u16* __restrict__ d2, int n2,
    const float* __restrict__ s3, u16* __restrict__ d3, int n3) {
  int ntot = n0 + n1 + n2 + n3;
  for (int i = blockIdx.x * 256 + threadIdx.x; i < ntot; i += gridDim.x * 256) {
    int j = i;
    const float* s; u16* d;
    if (j < n0) { s = s0; d = d0; }
    else {
      j -= n0;
      if (j < n1) { s = s1; d = d1; }
      else {
        j -= n1;
        if (j < n2) { s = s2; d = d2; }
        else { j -= n2; s = s3; d = d3; }
      }
    }
    const float4* sp = (const float4*)s + 2 * (size_t)j;
    float4 a = sp[0], b = sp[1];
    ((uint4*)d)[j] = make_uint4(pk2bf(a.x, a.y), pk2bf(a.z, a.w),
                                pk2bf(b.x, b.y), pk2bf(b.z, b.w));
  }
}

// in_W (768x54) -> bf16 transposed (64x768), rows j>=54 zero
__global__ __launch_bounds__(256) void pad_inwT_kernel(const float* __restrict__ src,
                                                       u16* __restrict__ dst) {
  int t = blockIdx.x * 256 + threadIdx.x;  // 64*768
  if (t >= 64 * 768) return;
  int j = t / 768, o = t - j * 768;
  dst[t] = (j < 54) ? f2bf(src[o * 54 + j]) : (u16)0;
}

// b'[m] = sum_o ca_qkv_W[768+m][o] * in_b[o] + ca_qkv_b[768+m]
__global__ __launch_bounds__(256) void bprime_kernel(const float* __restrict__ caW,
                                                     const float* __restrict__ caB,
                                                     const float* __restrict__ inb,
                                                     float* __restrict__ bp) {
  int w = threadIdx.x >> 6, lane = threadIdx.x & 63;
  int m = blockIdx.x * 4 + w;
  const float* row = caW + (size_t)(768 + m) * 768;
  float s = 0.f;
#pragma unroll
  for (int k = 0; k < 12; k++) s += row[lane + k * 64] * inb[lane + k * 64];
#pragma unroll
  for (int msk = 32; msk >= 1; msk >>= 1) s += __shfl_xor(s, msk, 64);
  if (lane == 0) bp[m] = s + caB[768 + m];
}

// ---------------- fourier embed ----------------
__global__ __launch_bounds__(256) void embed_kernel(const float* __restrict__ pc,
                                                    const float* __restrict__ feats,
                                                    u16* __restrict__ emb) {
  int t = blockIdx.x * 256 + threadIdx.x;
  int p = t >> 6, c = t & 63;
  float v = 0.f;
  if (c < 3) {
    v = pc[p * 3 + c];
  } else if (c < 27) {
    int i = c - 3;
    float f = (float)(1 << (i & 7));
    v = sinf(pc[p * 3 + (i >> 3)] * f);
  } else if (c < 51) {
    int i = c - 27;
    float f = (float)(1 << (i & 7));
    v = cosf(pc[p * 3 + (i >> 3)] * f);
  } else if (c < 54) {
    v = feats[p * 3 + (c - 51)];
  }
  emb[t] = f2bf(v);
}

// ---------------- templated GEMM (single-buffer structure) ----------------
// MODE 0: all tiles normal (operand-swapped MFMA, vectorized epilogue).
// MODE 1: y>=vy -> V transposed into vt[b*768+(n-vy*TN)][skvt] (cross KV, TN=128).
// MODE 2: y%3==2 -> V of head y/3 transposed into vt[(b*12+h)*64+d][skvt] (qkv, TN=64).
template <int TM, int TN, int WR, int WC, int MODE>
__global__ __launch_bounds__(256) void gemm_t(
    const u16* __restrict__ A, const u16* __restrict__ Bw,
    const float* __restrict__ bias, const float* __restrict__ resid,
    float* __restrict__ outF, u16* __restrict__ outB,
    int M, int N, int Nout, int K, int gelu,
    u16* __restrict__ vt, int vy, int skvt, int bsh) {
  constexpr int IM = TM / WR / 16;
  constexpr int IN = TN / WC / 16;
  __shared__ u16 As[TM * 32];
  __shared__ u16 Bs[TN * 32];
  const int tid = threadIdx.x;
  const int lane = tid & 63, w = tid >> 6;
  const int l15 = lane & 15, quad = lane >> 4;
  const int mblk = blockIdx.x * TM, nblk = blockIdx.y * TN;
  const int wm = (w % WR) * (TM / WR);
  const int wn = (w / WR) * (TN / WC);

  f32x4 acc[IM][IN];
#pragma unroll
  for (int i = 0; i < IM; i++)
#pragma unroll
    for (int j = 0; j < IN; j++) acc[i][j] = f32x4{0.f, 0.f, 0.f, 0.f};

  bool tv = false;
  if (MODE == 1) tv = ((int)blockIdx.y >= vy);
  if (MODE == 2) tv = ((int)(blockIdx.y % 3) == 2);

  if (!tv) {
    for (int k0 = 0; k0 < K; k0 += 32) {
#pragma unroll
      for (int s = tid; s < TM * 4; s += 256) {
        int row = s >> 2, c8 = (s & 3) << 3;
        gl2lds16(A + (size_t)(mblk + row) * K + (k0 + c8), &As[s * 8]);
      }
#pragma unroll
      for (int s = tid; s < TN * 4; s += 256) {
        int row = s >> 2, c8 = (s & 3) << 3;
        gl2lds16(Bw + (size_t)(nblk + row) * K + (k0 + c8), &Bs[s * 8]);
      }
      __syncthreads();
      bf16x8 af[IM], bfr[IN];
#pragma unroll
      for (int i = 0; i < IM; i++)
        af[i] = *(const bf16x8*)&As[(wm + i * 16 + l15) * 32 + quad * 8];
#pragma unroll
      for (int j = 0; j < IN; j++)
        bfr[j] = *(const bf16x8*)&Bs[(wn + j * 16 + l15) * 32 + quad * 8];
#pragma unroll
      for (int i = 0; i < IM; i++)
#pragma unroll
        for (int j = 0; j < IN; j++)
          acc[i][j] = __builtin_amdgcn_mfma_f32_16x16x32_bf16(bfr[j], af[i], acc[i][j], 0, 0, 0);
      __syncthreads();
    }
#pragma unroll
    for (int i = 0; i < IM; i++) {
      int m = mblk + wm + i * 16 + l15;
#pragma unroll
      for (int j = 0; j < IN; j++) {
        int n0 = nblk + wn + j * 16 + quad * 4;
        float4 bv = bias ? *(const float4*)&bias[n0] : make_float4(0.f, 0.f, 0.f, 0.f);
        float v0 = acc[i][j][0] + bv.x;
        float v1 = acc[i][j][1] + bv.y;
        float v2 = acc[i][j][2] + bv.z;
        float v3 = acc[i][j][3] + bv.w;
        if (gelu) {
          v0 = 0.5f * v0 * (1.0f + erff(v0 * 0.70710678118f));
          v1 = 0.5f * v1 * (1.0f + erff(v1 * 0.70710678118f));
          v2 = 0.5f * v2 * (1.0f + erff(v2 * 0.70710678118f));
          v3 = 0.5f * v3 * (1.0f + erff(v3 * 0.70710678118f));
        }
        size_t idx = (size_t)m * Nout + n0;
        if (resid) {
          float4 rv = *(const float4*)&resid[idx];
          v0 += rv.x; v1 += rv.y; v2 += rv.z; v3 += rv.w;
        }
        if (outF) {
          float4 ov = {v0, v1, v2, v3};
          *(float4*)&outF[idx] = ov;
        }
        if (outB) {
          *(uint2*)&outB[idx] = make_uint2(pk2bf(v0, v1), pk2bf(v2, v3));
        }
      }
    }
  } else {
    for (int k0 = 0; k0 < K; k0 += 32) {
#pragma unroll
      for (int s = tid; s < TM * 4; s += 256) {
        int row = s >> 2, c8 = (s & 3) << 3;
        gl2lds16(A + (size_t)(mblk + row) * K + (k0 + c8), &As[s * 8]);
      }
#pragma unroll
      for (int s = tid; s < TN * 4; s += 256) {
        int row = s >> 2, c8 = (s & 3) << 3;
        gl2lds16(Bw + (size_t)(nblk + row) * K + (k0 + c8), &Bs[s * 8]);
      }
      __syncthreads();
      bf16x8 af[IM], bfr[IN];
#pragma unroll
      for (int i = 0; i < IM; i++)
        af[i] = *(const bf16x8*)&As[(wm + i * 16 + l15) * 32 + quad * 8];
#pragma unroll
      for (int j = 0; j < IN; j++)
        bfr[j] = *(const bf16x8*)&Bs[(wn + j * 16 + l15) * 32 + quad * 8];
#pragma unroll
      for (int i = 0; i < IM; i++)
#pragma unroll
        for (int j = 0; j < IN; j++)
          acc[i][j] = __builtin_amdgcn_mfma_f32_16x16x32_bf16(af[i], bfr[j], acc[i][j], 0, 0, 0);
      __syncthreads();
    }
    int msk = (1 << bsh) - 1;
#pragma unroll
    for (int j = 0; j < IN; j++) {
      int n = nblk + wn + j * 16 + l15;
      float bv = bias ? bias[n] : 0.f;
#pragma unroll
      for (int i = 0; i < IM; i++) {
        int m0 = mblk + wm + i * 16 + quad * 4;
        int b = m0 >> bsh;
        int s0 = m0 & msk;
        float v0 = acc[i][j][0] + bv;
        float v1 = acc[i][j][1] + bv;
        float v2 = acc[i][j][2] + bv;
        float v3 = acc[i][j][3] + bv;
        size_t vrow;
        if (MODE == 2) {
          int h = blockIdx.y / 3;
          vrow = (size_t)(b * 12 + h) * 64 + (wn + j * 16 + l15);
        } else {
          vrow = (size_t)b * 768 + (n - vy * TN);
        }
        size_t addr = vrow * skvt + s0;
        *(uint2*)&vt[addr] = make_uint2(pk2bf(v0, v1), pk2bf(v2, v3));
      }
    }
  }
}

// ---------------- split-K GEMM: f32 partials, epilogue in skred_kernel ----------------
template <int TM, int TN, int WR, int WC>
__global__ __launch_bounds__(256) void gemmsk_t(
    const u16* __restrict__ A, const u16* __restrict__ Bw,
    float* __restrict__ P, int M, int N, int K, int kchunk) {
  constexpr int IM = TM / WR / 16;
  constexpr int IN = TN / WC / 16;
  __shared__ u16 As[TM * 32];
  __shared__ u16 Bs[TN * 32];
  const int tid = threadIdx.x;
  const int lane = tid & 63, w = tid >> 6;
  const int l15 = lane & 15, quad = lane >> 4;
  const int mblk = blockIdx.x * TM, nblk = blockIdx.y * TN;
  const int wm = (w % WR) * (TM / WR);
  const int wn = (w / WR) * (TN / WC);
  const int kbeg = blockIdx.z * kchunk;
  const int kend = kbeg + kchunk;

  f32x4 acc[IM][IN];
#pragma unroll
  for (int i = 0; i < IM; i++)
#pragma unroll
    for (int j = 0; j < IN; j++) acc[i][j] = f32x4{0.f, 0.f, 0.f, 0.f};

  for (int k0 = kbeg; k0 < kend; k0 += 32) {
#pragma unroll
    for (int s = tid; s < TM * 4; s += 256) {
      int row = s >> 2, c8 = (s & 3) << 3;
      gl2lds16(A + (size_t)(mblk + row) * K + (k0 + c8), &As[s * 8]);
    }
#pragma unroll
    for (int s = tid; s < TN * 4; s += 256) {
      int row = s >> 2, c8 = (s & 3) << 3;
      gl2lds16(Bw + (size_t)(nblk + row) * K + (k0 + c8), &Bs[s * 8]);
    }
    __syncthreads();
    bf16x8 af[IM], bfr[IN];
#pragma unroll
    for (int i = 0; i < IM; i++)
      af[i] = *(const bf16x8*)&As[(wm + i * 16 + l15) * 32 + quad * 8];
#pragma unroll
    for (int j = 0; j < IN; j++)
      bfr[j] = *(const bf16x8*)&Bs[(wn + j * 16 + l15) * 32 + quad * 8];
#pragma unroll
    for (int i = 0; i < IM; i++)
#pragma unroll
      for (int j = 0; j < IN; j++)
        acc[i][j] = __builtin_amdgcn_mfma_f32_16x16x32_bf16(bfr[j], af[i], acc[i][j], 0, 0, 0);
    __syncthreads();
  }

  float* Pz = P + (size_t)blockIdx.z * M * N;
#pragma unroll
  for (int i = 0; i < IM; i++) {
    int m = mblk + wm + i * 16 + l15;
#pragma unroll
    for (int j = 0; j < IN; j++) {
      int n0 = nblk + wn + j * 16 + quad * 4;
      float4 ov = {acc[i][j][0], acc[i][j][1], acc[i][j][2], acc[i][j][3]};
      *(float4*)&Pz[(size_t)m * N + n0] = ov;
    }
  }
}

// split-K reduce + epilogue (bias / resid / f32 and-or bf16 out)
__global__ __launch_bounds__(256) void skred_kernel(
    const float* __restrict__ P, int nsk, int MN4, int N,
    const float* __restrict__ bias, const float* __restrict__ resid,
    float* __restrict__ outF, u16* __restrict__ outB) {
  int i = blockIdx.x * 256 + threadIdx.x;
  if (i >= MN4) return;
  float4 s = ((const float4*)P)[i];
  for (int z = 1; z < nsk; z++) {
    float4 t = ((const float4*)P)[(size_t)z * MN4 + i];
    s.x += t.x; s.y += t.y; s.z += t.z; s.w += t.w;
  }
  if (bias) {
    int n0 = (i * 4) % N;
    float4 b = *(const float4*)&bias[n0];
    s.x += b.x; s.y += b.y; s.z += b.z; s.w += b.w;
  }
  if (resid) {
    float4 r = ((const float4*)resid)[i];
    s.x += r.x; s.y += r.y; s.z += r.z; s.w += r.w;
  }
  if (outF) ((float4*)outF)[i] = s;
  if (outB) ((uint2*)outB)[i] = make_uint2(pk2bf(s.x, s.y), pk2bf(s.z, s.w));
}

// ---------------- flash attention: swapped-S softmax, single-buffer K/V with
// register-staged prefetch (T14), Ps aliased onto Qs, defer-max ----------------
__global__ __launch_bounds__(256) void flash_kernel(
    const u16* __restrict__ Q, long qb, int qrs, int qhs,
    const u16* __restrict__ Kp, long kb, int krs, int khs,
    const u16* __restrict__ Vt, u16* __restrict__ Out,
    u16* __restrict__ Part, float* __restrict__ Ml,
    int Skv, int nsplit, int kvlen, int nbh, float scale2) {
  // 25600 B total: Ps(64x72) aliases Qs(64x64, prologue-only); K/V single-buffered
  __shared__ u16 SH[64 * 72 + 2 * 64 * 64];
  u16* const Qs = SH;
  u16* const Ps = SH;
  u16* const Ks = SH + 64 * 72;
  u16* const Vs = SH + 64 * 72 + 64 * 64;

  const int tid = threadIdx.x;
  const int lane = tid & 63, w = tid >> 6;
  const int l15 = lane & 15, quad = lane >> 4;

  int bid = blockIdx.x;
  int grp = nbh * nsplit;
  int qt = bid / grp;
  int rem = bid - qt * grp;
  int bh = rem / nsplit;
  int split = rem - bh * nsplit;
  int h = bh % 12, b = bh / 12;

  const u16* Qbase = Q + (size_t)b * qb + (size_t)(qt * 64) * qrs + h * qhs;
  const u16* Kbase = Kp + (size_t)b * kb + (size_t)h * khs;
  const u16* Vbase = Vt + ((size_t)(b * 12 + h) * 64) * Skv;

  int kt0 = split * kvlen;

  // prologue: stage Q + first K/V tile via global_load_lds
#pragma unroll
  for (int p = 0; p < 2; ++p) {
    int slot = tid + p * 256;
    int row = slot >> 3, c = slot & 7;
    int cg = (c - row) & 7;
    gl2lds16(Qbase + (size_t)row * qrs + cg * 8, &Qs[slot * 8]);
    gl2lds16(Kbase + (size_t)(kt0 + row) * krs + cg * 8, &Ks[slot * 8]);
    gl2lds16(Vbase + (size_t)row * Skv + kt0 + cg * 8, &Vs[slot * 8]);
  }
  __syncthreads();

  bf16x8 qa[2];
#pragma unroll
  for (int kk = 0; kk < 2; kk++)
    qa[kk] = *(const bf16x8*)&Qs[(w * 16 + l15) * 64 + ((kk * 4 + quad + l15) & 7) * 8];
  // Qs region is reused as Ps from iter 0 on — ensure every wave's Q reads retired
  waitlgkm0();
  bar();

  f32x4 zero = {0.f, 0.f, 0.f, 0.f};
  f32x4 O[4];
#pragma unroll
  for (int d = 0; d < 4; d++) O[d] = zero;
  float m_i = -1e30f, l_i = 0.f;   // per-lane: q-row = w*16 + l15

  // per-thread staging addresses (cg is identical for both row slots: 32 % 8 == 0)
  const int srow = tid >> 3;
  const int scg = ((tid & 7) - srow) & 7;

  for (int kt = kt0; kt < kt0 + kvlen; kt += 64) {
    bool hasnext = (kt + 64 < kt0 + kvlen);
    uint4 kreg0, kreg1, vreg0, vreg1;
    if (hasnext) {
      // issue next-tile loads into registers; they retire under this tile's compute
      kreg0 = *(const uint4*)(Kbase + (size_t)(kt + 64 + srow) * krs + scg * 8);
      kreg1 = *(const uint4*)(Kbase + (size_t)(kt + 64 + srow + 32) * krs + scg * 8);
      vreg0 = *(const uint4*)(Vbase + (size_t)srow * Skv + (kt + 64) + scg * 8);
      vreg1 = *(const uint4*)(Vbase + (size_t)(srow + 32) * Skv + (kt + 64) + scg * 8);
    }

    f32x4 St[4];
#pragma unroll
    for (int j = 0; j < 4; j++) St[j] = zero;
#pragma unroll
    for (int kk = 0; kk < 2; kk++) {
#pragma unroll
      for (int j = 0; j < 4; j++) {
        bf16x8 kf = *(const bf16x8*)&Ks[(j * 16 + l15) * 64 + ((kk * 4 + quad + l15) & 7) * 8];
        St[j] = __builtin_amdgcn_mfma_f32_16x16x32_bf16(kf, qa[kk], St[j], 0, 0, 0);
      }
    }

    // per-q-row max (lanes sharing l15 hold the same row; xor16/32 reduces them)
    float mx = St[0][0];
#pragma unroll
    for (int j = 0; j < 4; j++)
#pragma unroll
      for (int r = 0; r < 4; r++) mx = fmaxf(mx, St[j][r]);
    mx = fmaxf(mx, __shfl_xor(mx, 16, 64));
    mx = fmaxf(mx, __shfl_xor(mx, 32, 64));
    mx *= scale2;

    // defer-max: if no row in this wave grew past m_i+8, keep old max (skip rescale)
    bool skip = __all(mx <= m_i + 8.f);
    float al = 1.f;
    if (!skip) {
      float mnew = fmaxf(m_i, mx);
      al = __expf(m_i - mnew);
      m_i = mnew;
    }
    float mref = m_i;
    float sum = 0.f;
#pragma unroll
    for (int j = 0; j < 4; j++) {
      float p0 = __expf(fmaf(St[j][0], scale2, -mref));
      float p1 = __expf(fmaf(St[j][1], scale2, -mref));
      float p2 = __expf(fmaf(St[j][2], scale2, -mref));
      float p3 = __expf(fmaf(St[j][3], scale2, -mref));
      sum += (p0 + p1) + (p2 + p3);
      *(uint2*)&Ps[(w * 16 + l15) * 72 + j * 16 + quad * 4] =
          make_uint2(pk2bf(p0, p1), pk2bf(p2, p3));
    }
    sum += __shfl_xor(sum, 16, 64);
    sum += __shfl_xor(sum, 32, 64);

    if (skip) {
      l_i += sum;
    } else {
      l_i = l_i * al + sum;
      float a0 = __shfl(al, quad * 20 + 0, 64);
      float a1 = __shfl(al, quad * 20 + 1, 64);
      float a2 = __shfl(al, quad * 20 + 2, 64);
      float a3 = __shfl(al, quad * 20 + 3, 64);
#pragma unroll
      for (int d = 0; d < 4; d++) {
        O[d][0] *= a0; O[d][1] *= a1; O[d][2] *= a2; O[d][3] *= a3;
      }
    }
    waitlgkm0();   // Ps writes visible (intra-wave rows only)
#pragma unroll
    for (int kk = 0; kk < 2; kk++) {
      bf16x8 pa = *(const bf16x8*)&Ps[(w * 16 + l15) * 72 + kk * 32 + quad * 8];
#pragma unroll
      for (int d = 0; d < 4; d++) {
        bf16x8 vf = *(const bf16x8*)&Vs[(d * 16 + l15) * 64 + ((kk * 4 + quad + l15) & 7) * 8];
        O[d] = __builtin_amdgcn_mfma_f32_16x16x32_bf16(pa, vf, O[d], 0, 0, 0);
      }
    }

    if (hasnext) {
      bar();       // all waves done reading Ks/Vs of this tile
      // write prefetched tile (compiler inserts the vmcnt wait before first use)
      *(uint4*)&Ks[tid * 8] = kreg0;
      *(uint4*)&Ks[(tid + 256) * 8] = kreg1;
      *(uint4*)&Vs[tid * 8] = vreg0;
      *(uint4*)&Vs[(tid + 256) * 8] = vreg1;
      waitlgkm0();
      bar();       // writes visible to all waves
    }
  }

  float l0 = __shfl(l_i, quad * 20 + 0, 64);
  float l1 = __shfl(l_i, quad * 20 + 1, 64);
  float l2 = __shfl(l_i, quad * 20 + 2, 64);
  float l3 = __shfl(l_i, quad * 20 + 3, 64);

  if (nsplit == 1) {
    float inv0 = 1.f / l0, inv1 = 1.f / l1, inv2 = 1.f / l2, inv3 = 1.f / l3;
    u16* Ob = Out + ((size_t)(b * 256 + qt * 64 + w * 16 + quad * 4)) * 768 + h * 64 + l15;
#pragma unroll
    for (int d = 0; d < 4; d++) {
      Ob[(size_t)0 * 768 + d * 16] = f2bf(O[d][0] * inv0);
      Ob[(size_t)1 * 768 + d * 16] = f2bf(O[d][1] * inv1);
      Ob[(size_t)2 * 768 + d * 16] = f2bf(O[d][2] * inv2);
      Ob[(size_t)3 * 768 + d * 16] = f2bf(O[d][3] * inv3);
    }
  } else {
    float m0 = __shfl(m_i, quad * 20 + 0, 64);
    float m1 = __shfl(m_i, quad * 20 + 1, 64);
    float m2 = __shfl(m_i, quad * 20 + 2, 64);
    float m3 = __shfl(m_i, quad * 20 + 3, 64);
    u16* Pb = Part + ((size_t)(bh * 4 + qt) * nsplit + split) * 4096;
    int rowb = w * 16 + quad * 4;
#pragma unroll
    for (int d = 0; d < 4; d++) {
      Pb[(rowb + 0) * 64 + d * 16 + l15] = f2bf(O[d][0]);
      Pb[(rowb + 1) * 64 + d * 16 + l15] = f2bf(O[d][1]);
      Pb[(rowb + 2) * 64 + d * 16 + l15] = f2bf(O[d][2]);
      Pb[(rowb + 3) * 64 + d * 16 + l15] = f2bf(O[d][3]);
    }
    if (l15 == 0) {
      float* MlB = Ml + ((size_t)(bh * 4 + qt) * nsplit + split) * 128;
      MlB[rowb + 0] = m0; MlB[rowb + 1] = m1; MlB[rowb + 2] = m2; MlB[rowb + 3] = m3;
      MlB[64 + rowb + 0] = l0; MlB[64 + rowb + 1] = l1;
      MlB[64 + rowb + 2] = l2; MlB[64 + rowb + 3] = l3;
    }
  }
}

// ---------------- split-KV reduce ----------------
__global__ __launch_bounds__(256) void freduce_kernel(
    const u16* __restrict__ Part, const float* __restrict__ Ml,
    u16* __restrict__ Out, int nsplit) {
  int bid = blockIdx.x;
  int qt = bid & 3, bh = bid >> 2;
  int h = bh % 12, b = bh / 12;
  int tid = threadIdx.x;
  int r = tid >> 2, dc = tid & 3;
  const float* mlb = Ml + (size_t)(bh * 4 + qt) * nsplit * 128;
  float M = -1e30f;
  for (int s = 0; s < nsplit; s++) M = fmaxf(M, mlb[s * 128 + r]);
  float L = 0.f;
  float accv[16];
#pragma unroll
  for (int i = 0; i < 16; i++) accv[i] = 0.f;
  const u16* pb = Part + (size_t)(bh * 4 + qt) * nsplit * 4096 + r * 64 + dc * 16;
  for (int s = 0; s < nsplit; s++) {
    float wgt = __expf(mlb[s * 128 + r] - M);
    L += wgt * mlb[s * 128 + 64 + r];
    u16 tmp[16];
    *(uint4*)tmp = *(const uint4*)(pb + s * 4096);
    *(uint4*)(tmp + 8) = *(const uint4*)(pb + s * 4096 + 8);
#pragma unroll
    for (int i = 0; i < 16; i++) accv[i] += wgt * bf2f(tmp[i]);
  }
  float inv = 1.f / L;
  unsigned ot[8];
#pragma unroll
  for (int i = 0; i < 8; i++)
    ot[i] = pk2bf(accv[2 * i] * inv, accv[2 * i + 1] * inv);
  u16* ob = Out + ((size_t)(b * 256 + qt * 64 + r)) * 768 + h * 64 + dc * 16;
  *(uint4*)ob = *(uint4*)ot;
  *(uint4*)(ob + 8) = *(uint4*)(ot + 4);
}

// ---------------- LayerNorm ----------------
__global__ __launch_bounds__(256) void ln_kernel(const float* __restrict__ X,
                                                 const float* __restrict__ sc,
                                                 const float* __restrict__ bi,
                                                 u16* __restrict__ Hout) {
  int row = blockIdx.x;
  int tid = threadIdx.x;
  const float* x = X + (size_t)row * 768;
  float v0 = x[tid], v1 = x[tid + 256], v2 = x[tid + 512];
  float s = v0 + v1 + v2;
  float q = v0 * v0 + v1 * v1 + v2 * v2;
#pragma unroll
  for (int m = 1; m < 64; m <<= 1) {
    s += __shfl_xor(s, m, 64);
    q += __shfl_xor(q, m, 64);
  }
  __shared__ float rs[4], rq[4];
  if ((tid & 63) == 0) { rs[tid >> 6] = s; rq[tid >> 6] = q; }
  __syncthreads();
  s = rs[0] + rs[1] + rs[2] + rs[3];
  q = rq[0] + rq[1] + rq[2] + rq[3];
  float mu = s * (1.f / 768.f);
  float var = q * (1.f / 768.f) - mu * mu;
  float rstd = rsqrtf(var + 1e-5f);
  u16* ho = Hout + (size_t)row * 768;
  ho[tid]       = f2bf((v0 - mu) * rstd * sc[tid]       + bi[tid]);
  ho[tid + 256] = f2bf((v1 - mu) * rstd * sc[tid + 256] + bi[tid + 256]);
  ho[tid + 512] = f2bf((v2 - mu) * rstd * sc[tid + 512] + bi[tid + 512]);
}

__global__ __launch_bounds__(256) void copy4_kernel(const float* __restrict__ src,
                                                    float* __restrict__ dst, int n4) {
  int i = blockIdx.x * 256 + threadIdx.x;
  if (i < n4) ((float4*)dst)[i] = ((const float4*)src)[i];
}

// =====================================================================
extern "C" void kernel_launch(void* const* d_in, const int* in_sizes, int n_in,
                              void* d_out, int out_size, void* d_ws, size_t ws_size,
                              hipStream_t stream) {
  const float* pc        = (const float*)d_in[0];
  const float* feats     = (const float*)d_in[1];
  const float* query     = (const float*)d_in[2];
  const float* in_W      = (const float*)d_in[3];
  const float* in_b      = (const float*)d_in[4];
  const float* ca_qkv_W  = (const float*)d_in[5];
  const float* ca_qkv_b  = (const float*)d_in[6];
  const float* ca_proj_W = (const float*)d_in[7];
  const float* ca_proj_b = (const float*)d_in[8];
  const float* ln1_s     = (const float*)d_in[9];
  const float* ln1_b     = (const float*)d_in[10];
  const float* qkv_W     = (const float*)d_in[11];
  const float* qkv_b     = (const float*)d_in[12];
  const float* proj_W    = (const float*)d_in[13];
  const float* proj_b    = (const float*)d_in[14];
  const float* ln2_s     = (const float*)d_in[15];
  const float* ln2_b     = (const float*)d_in[16];
  const float* fc_W      = (const float*)d_in[17];
  const float* fc_b      = (const float*)d_in[18];
  const float* fc2_W     = (const float*)d_in[19];
  const float* fc2_b     = (const float*)d_in[20];

  char* base = (char*)d_ws;
  size_t off = 0;
  auto alloc = [&](size_t bytes) -> char* {
    char* p = base + off;
    off += (bytes + 255) & ~(size_t)255;
    return p;
  };

  // ---- fixed region ----
  u16* WqT     = (u16*)alloc(64 * 768 * 2);
  u16* Wquery  = (u16*)alloc(256 * 768 * 2);
  u16* Wcaqkv  = (u16*)alloc(2304 * 768 * 2);
  u16* Wcaproj = (u16*)alloc(768 * 768 * 2);
  u16* Wkp     = (u16*)alloc(1536 * 64 * 2);
  float* bprime = (float*)alloc(1536 * 4);
  u16* qc      = (u16*)alloc(256 * 768 * 2);
  u16* attn    = (u16*)alloc((size_t)2048 * 768 * 2);
  u16* hbuf    = (u16*)alloc((size_t)2048 * 768 * 2);
  char* uni    = alloc(13369344);
  u16* qkvb    = (u16*)uni;
  u16* VtS     = (u16*)(uni + 9437184);
  u16* fc1     = (u16*)uni;
  u16* Part    = (u16*)uni;
  float* Ml    = (float*)(uni + 12582912);

  size_t fixed_end = off;
  const size_t wAllSz = (size_t)8 * (2304 * 768 + 768 * 768 + 2 * 3072 * 768) * 2;
  auto crossSz = [](int cb) {
    return (size_t)cb * 4096 * 64 * 2 + 2 * ((size_t)cb * 4096 * 768 * 2);
  };

  bool allw; int CB;
  if (fixed_end + (wAllSz > crossSz(8) ? wAllSz : crossSz(8)) + 65536 <= ws_size) {
    allw = true;  CB = 8;
  } else if (fixed_end + 14155776 + crossSz(2) + 65536 <= ws_size) {
    allw = false; CB = 2;
  } else {
    allw = false; CB = 1;
  }

  u16 *WqkvB, *WprojB, *WfcB, *Wfc2B, *emb, *kvbK, *VtC;
  if (allw) {
    char* X = base + off;
    WqkvB  = (u16*)X;
    WprojB = WqkvB + (size_t)8 * 2304 * 768;
    WfcB   = WprojB + (size_t)8 * 768 * 768;
    Wfc2B  = WfcB + (size_t)8 * 3072 * 768;
    emb  = (u16*)X;
    kvbK = (u16*)(X + (size_t)CB * 4096 * 64 * 2);
    VtC  = (u16*)(X + (size_t)CB * 4096 * 64 * 2 + (size_t)CB * 4096 * 768 * 2);
    off = fixed_end + (wAllSz > crossSz(8) ? wAllSz : crossSz(8));
  } else {
    WqkvB  = (u16*)alloc(2304 * 768 * 2);
    WprojB = (u16*)alloc(768 * 768 * 2);
    WfcB   = (u16*)alloc(3072 * 768 * 2);
    Wfc2B  = (u16*)alloc((size_t)768 * 3072 * 2);
    emb  = (u16*)alloc((size_t)CB * 4096 * 64 * 2);
    kvbK = (u16*)alloc((size_t)CB * 4096 * 768 * 2);
    VtC  = (u16*)alloc((size_t)CB * 4096 * 768 * 2);
  }

  // ---- split-K partial buffer (adaptive: degrade if workspace is tight) ----
  const size_t pb2048 = (size_t)2048 * 768 * 4;   // one split of a 2048x768 f32 partial
  auto fits = [&](size_t bytes) { return off + bytes + 4096 <= ws_size; };
  int nsk_fc2 = fits(4 * pb2048) ? 4 : (fits(2 * pb2048) ? 2 : 1);
  int nsk_pr  = fits(2 * pb2048) ? 2 : 1;
  int nsk_qc  = fits((size_t)256 * 768 * 4 * 8) ? 8 : 1;
  float* skP  = (float*)(base + off);   // not bump-allocated; transient reuse

  float* latents = (float*)d_out;
  const float scale2 = 0.125f;

  // --- upfront conversions + fused-weight precompute ---
  {
    int n0 = 256 * 768 / 8, n1 = 2304 * 768 / 8, n2 = 768 * 768 / 8;
    int nt = n0 + n1 + n2;
    int g = (nt + 255) / 256; if (g > 4096) g = 4096;
    cvt8_kernel<<<g, 256, 0, stream>>>(
        query, Wquery, n0, ca_qkv_W, Wcaqkv, n1, ca_proj_W, Wcaproj, n2,
        nullptr, nullptr, 0);
  }
  pad_inwT_kernel<<<192, 256, 0, stream>>>(in_W, WqT);
  gemm_t<64, 64, 2, 2, 0><<<dim3(24, 1), 256, 0, stream>>>(
      Wcaqkv + (size_t)768 * 768, WqT, nullptr, nullptr, nullptr, Wkp,
      1536, 64, 64, 768, 0, nullptr, 0, 0, 0);
  bprime_kernel<<<384, 256, 0, stream>>>(ca_qkv_W, ca_qkv_b, in_b, bprime);

  // --- latent q projection (split-K: 48 blocks -> 384) ---
  if (nsk_qc > 1) {
    gemmsk_t<64, 64, 2, 2><<<dim3(4, 12, nsk_qc), 256, 0, stream>>>(
        Wquery, Wcaqkv, skP, 256, 768, 768, 768 / nsk_qc);
    skred_kernel<<<192, 256, 0, stream>>>(
        skP, nsk_qc, 256 * 768 / 4, 768, ca_qkv_b, nullptr, nullptr, qc);
  } else {
    gemm_t<64, 64, 2, 2, 0><<<dim3(4, 12), 256, 0, stream>>>(
        Wquery, Wcaqkv, ca_qkv_b, nullptr, nullptr, qc,
        256, 768, 768, 768, 0, nullptr, 0, 0, 0);
  }

  // --- cross-attention, chunked over batches ---
  int nchunk = 8 / CB;
  for (int c = 0; c < nchunk; ++c) {
    int Mc = CB * 4096;
    const float* pc_c = pc + (size_t)c * Mc * 3;
    const float* ft_c = feats + (size_t)c * Mc * 3;
    embed_kernel<<<Mc / 4, 256, 0, stream>>>(pc_c, ft_c, emb);
    gemm_t<128, 128, 2, 2, 1><<<dim3(Mc / 128, 12), 256, 0, stream>>>(
        emb, Wkp, bprime, nullptr, nullptr, kvbK,
        Mc, 1536, 768, 64, 0, VtC, 6, 4096, 12);
    flash_kernel<<<CB * 12 * 16, 256, 0, stream>>>(
        qc, 0L, 768, 64, kvbK, (long)4096 * 768, 768, 64, VtC,
        nullptr, Part, Ml, 4096, 4, 1024, CB * 12, scale2);
    freduce_kernel<<<CB * 48, 256, 0, stream>>>(
        Part, Ml, attn + (size_t)c * CB * 256 * 768, 4);
  }
  if (nsk_pr > 1) {
    gemmsk_t<128, 64, 2, 2><<<dim3(16, 12, nsk_pr), 256, 0, stream>>>(
        attn, Wcaproj, skP, 2048, 768, 768, 768 / nsk_pr);
    skred_kernel<<<1536, 256, 0, stream>>>(
        skP, nsk_pr, 2048 * 768 / 4, 768, ca_proj_b, nullptr, latents, nullptr);
  } else {
    gemm_t<128, 64, 2, 2, 0><<<dim3(16, 12), 256, 0, stream>>>(
        attn, Wcaproj, ca_proj_b, nullptr, latents, nullptr,
        2048, 768, 768, 768, 0, nullptr, 0, 0, 0);
  }

  // --- all-layer weight conversion (one vectorized sweep) ---
  if (allw) {
    int n0 = 8 * 2304 * 768 / 8, n1 = 8 * 768 * 768 / 8, n2 = 8 * 3072 * 768 / 8;
    cvt8_kernel<<<4096, 256, 0, stream>>>(
        qkv_W, WqkvB, n0, proj_W, WprojB, n1, fc_W, WfcB, n2, fc2_W, Wfc2B, n2);
  }

  // --- transformer layers ---
  for (int l = 0; l < 8; ++l) {
    u16* Wlq  = allw ? WqkvB  + (size_t)l * 2304 * 768 : WqkvB;
    u16* Wlp  = allw ? WprojB + (size_t)l * 768 * 768  : WprojB;
    u16* Wlf  = allw ? WfcB   + (size_t)l * 3072 * 768 : WfcB;
    u16* Wlf2 = allw ? Wfc2B  + (size_t)l * 3072 * 768 : Wfc2B;
    if (!allw) {
      int n0 = 2304 * 768 / 8, n1 = 768 * 768 / 8, n2 = 3072 * 768 / 8;
      int g = (n0 + n1 + 2 * n2 + 255) / 256; if (g > 4096) g = 4096;
      cvt8_kernel<<<g, 256, 0, stream>>>(
          qkv_W + (size_t)l * 2304 * 768, Wlq, n0,
          proj_W + (size_t)l * 768 * 768, Wlp, n1,
          fc_W + (size_t)l * 3072 * 768, Wlf, n2,
          fc2_W + (size_t)l * 768 * 3072, Wlf2, n2);
    }
    ln_kernel<<<2048, 256, 0, stream>>>(latents, ln1_s + l * 768, ln1_b + l * 768, hbuf);
    // qkv GEMM with fused V^T write (tiles y%3==2 go straight to VtS); 128-row tile
    gemm_t<128, 64, 2, 2, 2><<<dim3(16, 36), 256, 0, stream>>>(
        hbuf, Wlq, qkv_b + l * 2304, nullptr, nullptr, qkvb,
        2048, 2304, 2304, 768, 0, VtS, 0, 256, 8);
    flash_kernel<<<384, 256, 0, stream>>>(
        qkvb, (long)256 * 2304, 2304, 192, qkvb + 64, (long)256 * 2304, 2304, 192,
        VtS, attn, nullptr, nullptr, 256, 1, 256, 96, scale2);
    // proj (+resid) via split-K; 128-row tile
    if (nsk_pr > 1) {
      gemmsk_t<128, 64, 2, 2><<<dim3(16, 12, nsk_pr), 256, 0, stream>>>(
          attn, Wlp, skP, 2048, 768, 768, 768 / nsk_pr);
      skred_kernel<<<1536, 256, 0, stream>>>(
          skP, nsk_pr, 2048 * 768 / 4, 768, proj_b + l * 768, latents, latents, nullptr);
    } else {
      gemm_t<128, 64, 2, 2, 0><<<dim3(16, 12), 256, 0, stream>>>(
          attn, Wlp, proj_b + l * 768, latents, latents, nullptr,
          2048, 768, 768, 768, 0, nullptr, 0, 0, 0);
    }
    ln_kernel<<<2048, 256, 0, stream>>>(latents, ln2_s + l * 768, ln2_b + l * 768, hbuf);
    // fc1: 128x128 tile
    gemm_t<128, 128, 2, 2, 0><<<dim3(16, 24), 256, 0, stream>>>(
        hbuf, Wlf, fc_b + l * 3072, nullptr, nullptr, fc1,
        2048, 3072, 3072, 768, 1, nullptr, 0, 0, 0);
    // fc2 (+resid) via split-K (K=3072); 128-row tile
    if (nsk_fc2 > 1) {
      gemmsk_t<128, 64, 2, 2><<<dim3(16, 12, nsk_fc2), 256, 0, stream>>>(
          fc1, Wlf2, skP, 2048, 768, 3072, 3072 / nsk_fc2);
      skred_kernel<<<1536, 256, 0, stream>>>(
          skP, nsk_fc2, 2048 * 768 / 4, 768, fc2_b + l * 768, latents, latents, nullptr);
    } else {
      gemm_t<128, 64, 2, 2, 0><<<dim3(16, 12), 256, 0, stream>>>(
          fc1, Wlf2, fc2_b + l * 768, latents, latents, nullptr,
          2048, 768, 768, 3072, 0, nullptr, 0, 0, 0);
    }
  }

  // --- second output: pc passthrough ---
  copy4_kernel<<<96, 256, 0, stream>>>(pc, (float*)d_out + (size_t)2048 * 768, 98304 / 4);
}

// Round 8
// 1265.085 us; speedup vs baseline: 1.0688x; 1.0688x over previous
//
#include <hip/hip_runtime.h>
#include <stdint.h>

typedef unsigned short u16;
typedef __bf16 bf16x8 __attribute__((ext_vector_type(8)));
typedef float f32x4 __attribute__((ext_vector_type(4)));

#define DEVINL __device__ __forceinline__

DEVINL u16 f2bf(float f) {
  union { float f; unsigned u; } c; c.f = f;
  unsigned u = c.u + 0x7FFFu + ((c.u >> 16) & 1u);
  return (u16)(u >> 16);
}

DEVINL float bf2f(u16 v) {
  union { unsigned u; float f; } c; c.u = (unsigned)v << 16;
  return c.f;
}

// packed fp32x2 -> bf16x2 (HW instruction when available; RNE either way)
DEVINL unsigned pk2bf(float a, float b) {
#if __has_builtin(__builtin_amdgcn_cvt_pk_bf16_f32)
  auto r = __builtin_amdgcn_cvt_pk_bf16_f32(a, b);
  unsigned u;
  __builtin_memcpy(&u, &r, 4);
  return u;
#else
  return (unsigned)f2bf(a) | ((unsigned)f2bf(b) << 16);
#endif
}

DEVINL void gl2lds16(const void* g, void* l) {
  __builtin_amdgcn_global_load_lds(
      (const __attribute__((address_space(1))) unsigned int*)g,
      (__attribute__((address_space(3))) unsigned int*)l, 16, 0, 0);
}

// counted vmcnt wait (loads newer than N stay outstanding; retire in order)
template <int N> DEVINL void waitvm() {
  asm volatile("s_waitcnt vmcnt(%0)" ::"n"(N) : "memory");
}
// raw barrier WITHOUT the __syncthreads vmcnt(0) drain
DEVINL void bar() {
  asm volatile("" ::: "memory");
  __builtin_amdgcn_s_barrier();
  asm volatile("" ::: "memory");
}

// ---------------- fused 4-segment fp32 -> bf16 conversion ----------------
__global__ __launch_bounds__(256) void cvt4_kernel(
    const float* __restrict__ s0, u16* __restrict__ d0, int n0,
    const float* __restrict__ s1, u16* __restrict__ d1, int n1,
    const float* __restrict__ s2, u16* __restrict__ d2, int n2,
    const float* __restrict__ s3, u16* __restrict__ d3, int n3) {
  int i = blockIdx.x * 256 + threadIdx.x;
  const float* s; u16* d;
  if (i < n0) { s = s0; d = d0; }
  else {
    i -= n0;
    if (i < n1) { s = s1; d = d1; }
    else {
      i -= n1;
      if (i < n2) { s = s2; d = d2; }
      else {
        i -= n2;
        if (i >= n3) return;
        s = s3; d = d3;
      }
    }
  }
  float4 v = ((const float4*)s)[i];
  ((uint2*)d)[i] = make_uint2(pk2bf(v.x, v.y), pk2bf(v.z, v.w));
}

// in_W (768x54) -> bf16 transposed (64x768), rows j>=54 zero
__global__ __launch_bounds__(256) void pad_inwT_kernel(const float* __restrict__ src,
                                                       u16* __restrict__ dst) {
  int t = blockIdx.x * 256 + threadIdx.x;  // 64*768
  if (t >= 64 * 768) return;
  int j = t / 768, o = t - j * 768;
  dst[t] = (j < 54) ? f2bf(src[o * 54 + j]) : (u16)0;
}

// b'[m] = sum_o ca_qkv_W[768+m][o] * in_b[o] + ca_qkv_b[768+m]
__global__ __launch_bounds__(256) void bprime_kernel(const float* __restrict__ caW,
                                                     const float* __restrict__ caB,
                                                     const float* __restrict__ inb,
                                                     float* __restrict__ bp) {
  int w = threadIdx.x >> 6, lane = threadIdx.x & 63;
  int m = blockIdx.x * 4 + w;
  const float* row = caW + (size_t)(768 + m) * 768;
  float s = 0.f;
#pragma unroll
  for (int k = 0; k < 12; k++) s += row[lane + k * 64] * inb[lane + k * 64];
#pragma unroll
  for (int msk = 32; msk >= 1; msk >>= 1) s += __shfl_xor(s, msk, 64);
  if (lane == 0) bp[m] = s + caB[768 + m];
}

// ---------------- fourier embed ----------------
__global__ __launch_bounds__(256) void embed_kernel(const float* __restrict__ pc,
                                                    const float* __restrict__ feats,
                                                    u16* __restrict__ emb) {
  int t = blockIdx.x * 256 + threadIdx.x;
  int p = t >> 6, c = t & 63;
  float v = 0.f;
  if (c < 3) {
    v = pc[p * 3 + c];
  } else if (c < 27) {
    int i = c - 3;
    float f = (float)(1 << (i & 7));
    v = sinf(pc[p * 3 + (i >> 3)] * f);
  } else if (c < 51) {
    int i = c - 27;
    float f = (float)(1 << (i & 7));
    v = cosf(pc[p * 3 + (i >> 3)] * f);
  } else if (c < 54) {
    v = feats[p * 3 + (c - 51)];
  }
  emb[t] = f2bf(v);
}

// ---------------- templated GEMM (single-buffer structure) ----------------
// MODE 0: all tiles normal (operand-swapped MFMA, vectorized epilogue).
// MODE 1: y>=vy -> V transposed into vt[b*768+(n-vy*TN)][skvt] (cross KV, TN=128).
// MODE 2: y%3==2 -> V of head y/3 transposed into vt[(b*12+h)*64+d][skvt] (qkv, TN=64).
template <int TM, int TN, int WR, int WC, int MODE>
__global__ __launch_bounds__(256) void gemm_t(
    const u16* __restrict__ A, const u16* __restrict__ Bw,
    const float* __restrict__ bias, const float* __restrict__ resid,
    float* __restrict__ outF, u16* __restrict__ outB,
    int M, int N, int Nout, int K, int gelu,
    u16* __restrict__ vt, int vy, int skvt, int bsh) {
  constexpr int IM = TM / WR / 16;
  constexpr int IN = TN / WC / 16;
  __shared__ u16 As[TM * 32];
  __shared__ u16 Bs[TN * 32];
  const int tid = threadIdx.x;
  const int lane = tid & 63, w = tid >> 6;
  const int l15 = lane & 15, quad = lane >> 4;
  const int mblk = blockIdx.x * TM, nblk = blockIdx.y * TN;
  const int wm = (w % WR) * (TM / WR);
  const int wn = (w / WR) * (TN / WC);

  f32x4 acc[IM][IN];
#pragma unroll
  for (int i = 0; i < IM; i++)
#pragma unroll
    for (int j = 0; j < IN; j++) acc[i][j] = f32x4{0.f, 0.f, 0.f, 0.f};

  bool tv = false;
  if (MODE == 1) tv = ((int)blockIdx.y >= vy);
  if (MODE == 2) tv = ((int)(blockIdx.y % 3) == 2);

  if (!tv) {
    for (int k0 = 0; k0 < K; k0 += 32) {
#pragma unroll
      for (int s = tid; s < TM * 4; s += 256) {
        int row = s >> 2, c8 = (s & 3) << 3;
        gl2lds16(A + (size_t)(mblk + row) * K + (k0 + c8), &As[s * 8]);
      }
#pragma unroll
      for (int s = tid; s < TN * 4; s += 256) {
        int row = s >> 2, c8 = (s & 3) << 3;
        gl2lds16(Bw + (size_t)(nblk + row) * K + (k0 + c8), &Bs[s * 8]);
      }
      __syncthreads();
      bf16x8 af[IM], bfr[IN];
#pragma unroll
      for (int i = 0; i < IM; i++)
        af[i] = *(const bf16x8*)&As[(wm + i * 16 + l15) * 32 + quad * 8];
#pragma unroll
      for (int j = 0; j < IN; j++)
        bfr[j] = *(const bf16x8*)&Bs[(wn + j * 16 + l15) * 32 + quad * 8];
#pragma unroll
      for (int i = 0; i < IM; i++)
#pragma unroll
        for (int j = 0; j < IN; j++)
          acc[i][j] = __builtin_amdgcn_mfma_f32_16x16x32_bf16(bfr[j], af[i], acc[i][j], 0, 0, 0);
      __syncthreads();
    }
#pragma unroll
    for (int i = 0; i < IM; i++) {
      int m = mblk + wm + i * 16 + l15;
#pragma unroll
      for (int j = 0; j < IN; j++) {
        int n0 = nblk + wn + j * 16 + quad * 4;
        float4 bv = bias ? *(const float4*)&bias[n0] : make_float4(0.f, 0.f, 0.f, 0.f);
        float v0 = acc[i][j][0] + bv.x;
        float v1 = acc[i][j][1] + bv.y;
        float v2 = acc[i][j][2] + bv.z;
        float v3 = acc[i][j][3] + bv.w;
        if (gelu) {
          v0 = 0.5f * v0 * (1.0f + erff(v0 * 0.70710678118f));
          v1 = 0.5f * v1 * (1.0f + erff(v1 * 0.70710678118f));
          v2 = 0.5f * v2 * (1.0f + erff(v2 * 0.70710678118f));
          v3 = 0.5f * v3 * (1.0f + erff(v3 * 0.70710678118f));
        }
        size_t idx = (size_t)m * Nout + n0;
        if (resid) {
          float4 rv = *(const float4*)&resid[idx];
          v0 += rv.x; v1 += rv.y; v2 += rv.z; v3 += rv.w;
        }
        if (outF) {
          float4 ov = {v0, v1, v2, v3};
          *(float4*)&outF[idx] = ov;
        }
        if (outB) {
          *(uint2*)&outB[idx] = make_uint2(pk2bf(v0, v1), pk2bf(v2, v3));
        }
      }
    }
  } else {
    for (int k0 = 0; k0 < K; k0 += 32) {
#pragma unroll
      for (int s = tid; s < TM * 4; s += 256) {
        int row = s >> 2, c8 = (s & 3) << 3;
        gl2lds16(A + (size_t)(mblk + row) * K + (k0 + c8), &As[s * 8]);
      }
#pragma unroll
      for (int s = tid; s < TN * 4; s += 256) {
        int row = s >> 2, c8 = (s & 3) << 3;
        gl2lds16(Bw + (size_t)(nblk + row) * K + (k0 + c8), &Bs[s * 8]);
      }
      __syncthreads();
      bf16x8 af[IM], bfr[IN];
#pragma unroll
      for (int i = 0; i < IM; i++)
        af[i] = *(const bf16x8*)&As[(wm + i * 16 + l15) * 32 + quad * 8];
#pragma unroll
      for (int j = 0; j < IN; j++)
        bfr[j] = *(const bf16x8*)&Bs[(wn + j * 16 + l15) * 32 + quad * 8];
#pragma unroll
      for (int i = 0; i < IM; i++)
#pragma unroll
        for (int j = 0; j < IN; j++)
          acc[i][j] = __builtin_amdgcn_mfma_f32_16x16x32_bf16(af[i], bfr[j], acc[i][j], 0, 0, 0);
      __syncthreads();
    }
    int msk = (1 << bsh) - 1;
#pragma unroll
    for (int j = 0; j < IN; j++) {
      int n = nblk + wn + j * 16 + l15;
      float bv = bias ? bias[n] : 0.f;
#pragma unroll
      for (int i = 0; i < IM; i++) {
        int m0 = mblk + wm + i * 16 + quad * 4;
        int b = m0 >> bsh;
        int s0 = m0 & msk;
        float v0 = acc[i][j][0] + bv;
        float v1 = acc[i][j][1] + bv;
        float v2 = acc[i][j][2] + bv;
        float v3 = acc[i][j][3] + bv;
        size_t vrow;
        if (MODE == 2) {
          int h = blockIdx.y / 3;
          vrow = (size_t)(b * 12 + h) * 64 + (wn + j * 16 + l15);
        } else {
          vrow = (size_t)b * 768 + (n - vy * TN);
        }
        size_t addr = vrow * skvt + s0;
        *(uint2*)&vt[addr] = make_uint2(pk2bf(v0, v1), pk2bf(v2, v3));
      }
    }
  }
}

// ---------------- split-K GEMM: f32 partials, epilogue in skred/skredln ----------------
template <int TM, int TN, int WR, int WC>
__global__ __launch_bounds__(256) void gemmsk_t(
    const u16* __restrict__ A, const u16* __restrict__ Bw,
    float* __restrict__ P, int M, int N, int K, int kchunk) {
  constexpr int IM = TM / WR / 16;
  constexpr int IN = TN / WC / 16;
  __shared__ u16 As[TM * 32];
  __shared__ u16 Bs[TN * 32];
  const int tid = threadIdx.x;
  const int lane = tid & 63, w = tid >> 6;
  const int l15 = lane & 15, quad = lane >> 4;
  const int mblk = blockIdx.x * TM, nblk = blockIdx.y * TN;
  const int wm = (w % WR) * (TM / WR);
  const int wn = (w / WR) * (TN / WC);
  const int kbeg = blockIdx.z * kchunk;
  const int kend = kbeg + kchunk;

  f32x4 acc[IM][IN];
#pragma unroll
  for (int i = 0; i < IM; i++)
#pragma unroll
    for (int j = 0; j < IN; j++) acc[i][j] = f32x4{0.f, 0.f, 0.f, 0.f};

  for (int k0 = kbeg; k0 < kend; k0 += 32) {
#pragma unroll
    for (int s = tid; s < TM * 4; s += 256) {
      int row = s >> 2, c8 = (s & 3) << 3;
      gl2lds16(A + (size_t)(mblk + row) * K + (k0 + c8), &As[s * 8]);
    }
#pragma unroll
    for (int s = tid; s < TN * 4; s += 256) {
      int row = s >> 2, c8 = (s & 3) << 3;
      gl2lds16(Bw + (size_t)(nblk + row) * K + (k0 + c8), &Bs[s * 8]);
    }
    __syncthreads();
    bf16x8 af[IM], bfr[IN];
#pragma unroll
    for (int i = 0; i < IM; i++)
      af[i] = *(const bf16x8*)&As[(wm + i * 16 + l15) * 32 + quad * 8];
#pragma unroll
    for (int j = 0; j < IN; j++)
      bfr[j] = *(const bf16x8*)&Bs[(wn + j * 16 + l15) * 32 + quad * 8];
#pragma unroll
    for (int i = 0; i < IM; i++)
#pragma unroll
      for (int j = 0; j < IN; j++)
        acc[i][j] = __builtin_amdgcn_mfma_f32_16x16x32_bf16(bfr[j], af[i], acc[i][j], 0, 0, 0);
    __syncthreads();
  }

  float* Pz = P + (size_t)blockIdx.z * M * N;
#pragma unroll
  for (int i = 0; i < IM; i++) {
    int m = mblk + wm + i * 16 + l15;
#pragma unroll
    for (int j = 0; j < IN; j++) {
      int n0 = nblk + wn + j * 16 + quad * 4;
      float4 ov = {acc[i][j][0], acc[i][j][1], acc[i][j][2], acc[i][j][3]};
      *(float4*)&Pz[(size_t)m * N + n0] = ov;
    }
  }
}

// split-K reduce + epilogue (bias / resid / f32 and-or bf16 out)
__global__ __launch_bounds__(256) void skred_kernel(
    const float* __restrict__ P, int nsk, int MN4, int N,
    const float* __restrict__ bias, const float* __restrict__ resid,
    float* __restrict__ outF, u16* __restrict__ outB) {
  int i = blockIdx.x * 256 + threadIdx.x;
  if (i >= MN4) return;
  float4 s = ((const float4*)P)[i];
  for (int z = 1; z < nsk; z++) {
    float4 t = ((const float4*)P)[(size_t)z * MN4 + i];
    s.x += t.x; s.y += t.y; s.z += t.z; s.w += t.w;
  }
  if (bias) {
    int n0 = (i * 4) % N;
    float4 b = *(const float4*)&bias[n0];
    s.x += b.x; s.y += b.y; s.z += b.z; s.w += b.w;
  }
  if (resid) {
    float4 r = ((const float4*)resid)[i];
    s.x += r.x; s.y += r.y; s.z += r.z; s.w += r.w;
  }
  if (outF) ((float4*)outF)[i] = s;
  if (outB) ((uint2*)outB)[i] = make_uint2(pk2bf(s.x, s.y), pk2bf(s.z, s.w));
}

// split-K reduce + bias + resid + latents write + FUSED LayerNorm -> hbuf bf16.
// One row (768 cols) per block; sc/bi/Hout may be null (skip LN tail).
__global__ __launch_bounds__(256) void skredln_kernel(
    const float* __restrict__ P, int nsk, int MN,
    const float* __restrict__ bias, const float* __restrict__ resid,
    const float* __restrict__ sc, const float* __restrict__ bi,
    float* __restrict__ outF, u16* __restrict__ Hout) {
  int row = blockIdx.x, tid = threadIdx.x;
  size_t base = (size_t)row * 768;
  float v0 = P[base + tid], v1 = P[base + tid + 256], v2 = P[base + tid + 512];
  for (int z = 1; z < nsk; z++) {
    const float* Pz = P + (size_t)z * MN;
    v0 += Pz[base + tid]; v1 += Pz[base + tid + 256]; v2 += Pz[base + tid + 512];
  }
  v0 += bias[tid]; v1 += bias[tid + 256]; v2 += bias[tid + 512];
  if (resid) {
    v0 += resid[base + tid]; v1 += resid[base + tid + 256]; v2 += resid[base + tid + 512];
  }
  outF[base + tid] = v0;
  outF[base + tid + 256] = v1;
  outF[base + tid + 512] = v2;
  if (Hout) {
    float s = v0 + v1 + v2;
    float q = v0 * v0 + v1 * v1 + v2 * v2;
#pragma unroll
    for (int m = 1; m < 64; m <<= 1) {
      s += __shfl_xor(s, m, 64);
      q += __shfl_xor(q, m, 64);
    }
    __shared__ float rs[4], rq[4];
    if ((tid & 63) == 0) { rs[tid >> 6] = s; rq[tid >> 6] = q; }
    __syncthreads();
    s = rs[0] + rs[1] + rs[2] + rs[3];
    q = rq[0] + rq[1] + rq[2] + rq[3];
    float mu = s * (1.f / 768.f);
    float var = q * (1.f / 768.f) - mu * mu;
    float rstd = rsqrtf(var + 1e-5f);
    u16* ho = Hout + base;
    ho[tid]       = f2bf((v0 - mu) * rstd * sc[tid]       + bi[tid]);
    ho[tid + 256] = f2bf((v1 - mu) * rstd * sc[tid + 256] + bi[tid + 256]);
    ho[tid + 512] = f2bf((v2 - mu) * rstd * sc[tid + 512] + bi[tid + 512]);
  }
}

// ---------------- flash attention: swapped-S softmax, counted-vmcnt K/V dbuf,
// defer-max (skip O-rescale when tile max <= m_i + 8) ----------------
__global__ __launch_bounds__(256) void flash_kernel(
    const u16* __restrict__ Q, long qb, int qrs, int qhs,
    const u16* __restrict__ Kp, long kb, int krs, int khs,
    const u16* __restrict__ Vt, u16* __restrict__ Out,
    u16* __restrict__ Part, float* __restrict__ Ml,
    int Skv, int nsplit, int kvlen, int nbh, float scale2) {
  __shared__ u16 Qs[64 * 64];
  __shared__ u16 Ks[2][64 * 64];
  __shared__ u16 Vs[2][64 * 64];
  __shared__ u16 Ps[64 * 72];

  const int tid = threadIdx.x;
  const int lane = tid & 63, w = tid >> 6;
  const int l15 = lane & 15, quad = lane >> 4;

  int bid = blockIdx.x;
  int grp = nbh * nsplit;
  int qt = bid / grp;
  int rem = bid - qt * grp;
  int bh = rem / nsplit;
  int split = rem - bh * nsplit;
  int h = bh % 12, b = bh / 12;

  const u16* Qbase = Q + (size_t)b * qb + (size_t)(qt * 64) * qrs + h * qhs;
  const u16* Kbase = Kp + (size_t)b * kb + (size_t)h * khs;
  const u16* Vbase = Vt + ((size_t)(b * 12 + h) * 64) * Skv;

  int kt0 = split * kvlen;

  // prologue: stage Q + first K/V tile together
#pragma unroll
  for (int p = 0; p < 2; ++p) {
    int slot = tid + p * 256;
    int row = slot >> 3, c = slot & 7;
    int cg = (c - row) & 7;
    gl2lds16(Qbase + (size_t)row * qrs + cg * 8, &Qs[slot * 8]);
    gl2lds16(Kbase + (size_t)(kt0 + row) * krs + cg * 8, &Ks[0][slot * 8]);
    gl2lds16(Vbase + (size_t)row * Skv + kt0 + cg * 8, &Vs[0][slot * 8]);
  }
  __syncthreads();

  bf16x8 qa[2];
#pragma unroll
  for (int kk = 0; kk < 2; kk++)
    qa[kk] = *(const bf16x8*)&Qs[(w * 16 + l15) * 64 + ((kk * 4 + quad + l15) & 7) * 8];

  f32x4 zero = {0.f, 0.f, 0.f, 0.f};
  f32x4 O[4];
#pragma unroll
  for (int d = 0; d < 4; d++) O[d] = zero;
  float m_i = -1e30f, l_i = 0.f;   // per-lane: q-row = w*16 + l15

  int cur = 0;
  for (int kt = kt0; kt < kt0 + kvlen; kt += 64) {
    bool hasnext = (kt + 64 < kt0 + kvlen);
    if (hasnext) {
#pragma unroll
      for (int p = 0; p < 2; ++p) {
        int slot = tid + p * 256;
        int row = slot >> 3, c = slot & 7;
        int cg = (c - row) & 7;
        gl2lds16(Kbase + (size_t)(kt + 64 + row) * krs + cg * 8, &Ks[cur ^ 1][slot * 8]);
        gl2lds16(Vbase + (size_t)row * Skv + (kt + 64) + cg * 8, &Vs[cur ^ 1][slot * 8]);
      }
      waitvm<4>();   // current tile done; next tile's 4 loads outstanding
    } else {
      waitvm<0>();
    }
    bar();           // current tile visible to all waves

    f32x4 St[4];
#pragma unroll
    for (int j = 0; j < 4; j++) St[j] = zero;
#pragma unroll
    for (int kk = 0; kk < 2; kk++) {
#pragma unroll
      for (int j = 0; j < 4; j++) {
        bf16x8 kf = *(const bf16x8*)&Ks[cur][(j * 16 + l15) * 64 + ((kk * 4 + quad + l15) & 7) * 8];
        St[j] = __builtin_amdgcn_mfma_f32_16x16x32_bf16(kf, qa[kk], St[j], 0, 0, 0);
      }
    }

    // per-q-row max (lanes sharing l15 hold the same row; xor16/32 reduces them)
    float mx = St[0][0];
#pragma unroll
    for (int j = 0; j < 4; j++)
#pragma unroll
      for (int r = 0; r < 4; r++) mx = fmaxf(mx, St[j][r]);
    mx = fmaxf(mx, __shfl_xor(mx, 16, 64));
    mx = fmaxf(mx, __shfl_xor(mx, 32, 64));
    mx *= scale2;

    // defer-max: if no row in this wave grew past m_i+8, keep old max (skip rescale)
    bool skip = __all(mx <= m_i + 8.f);
    float al = 1.f;
    if (!skip) {
      float mnew = fmaxf(m_i, mx);
      al = __expf(m_i - mnew);
      m_i = mnew;
    }
    float mref = m_i;
    float sum = 0.f;
#pragma unroll
    for (int j = 0; j < 4; j++) {
      float p0 = __expf(fmaf(St[j][0], scale2, -mref));
      float p1 = __expf(fmaf(St[j][1], scale2, -mref));
      float p2 = __expf(fmaf(St[j][2], scale2, -mref));
      float p3 = __expf(fmaf(St[j][3], scale2, -mref));
      sum += (p0 + p1) + (p2 + p3);
      *(uint2*)&Ps[(w * 16 + l15) * 72 + j * 16 + quad * 4] =
          make_uint2(pk2bf(p0, p1), pk2bf(p2, p3));
    }
    sum += __shfl_xor(sum, 16, 64);
    sum += __shfl_xor(sum, 32, 64);

    if (skip) {
      l_i += sum;
    } else {
      l_i = l_i * al + sum;
      float a0 = __shfl(al, quad * 20 + 0, 64);
      float a1 = __shfl(al, quad * 20 + 1, 64);
      float a2 = __shfl(al, quad * 20 + 2, 64);
      float a3 = __shfl(al, quad * 20 + 3, 64);
#pragma unroll
      for (int d = 0; d < 4; d++) {
        O[d][0] *= a0; O[d][1] *= a1; O[d][2] *= a2; O[d][3] *= a3;
      }
    }
    __asm__ __volatile__("s_waitcnt lgkmcnt(0)" ::: "memory");
#pragma unroll
    for (int kk = 0; kk < 2; kk++) {
      bf16x8 pa = *(const bf16x8*)&Ps[(w * 16 + l15) * 72 + kk * 32 + quad * 8];
#pragma unroll
      for (int d = 0; d < 4; d++) {
        bf16x8 vf = *(const bf16x8*)&Vs[cur][(d * 16 + l15) * 64 + ((kk * 4 + quad + l15) & 7) * 8];
        O[d] = __builtin_amdgcn_mfma_f32_16x16x32_bf16(pa, vf, O[d], 0, 0, 0);
      }
    }
    bar();           // all reads of buffer `cur` done before it is re-staged
    cur ^= 1;
  }

  float l0 = __shfl(l_i, quad * 20 + 0, 64);
  float l1 = __shfl(l_i, quad * 20 + 1, 64);
  float l2 = __shfl(l_i, quad * 20 + 2, 64);
  float l3 = __shfl(l_i, quad * 20 + 3, 64);

  if (nsplit == 1) {
    float inv0 = 1.f / l0, inv1 = 1.f / l1, inv2 = 1.f / l2, inv3 = 1.f / l3;
    u16* Ob = Out + ((size_t)(b * 256 + qt * 64 + w * 16 + quad * 4)) * 768 + h * 64 + l15;
#pragma unroll
    for (int d = 0; d < 4; d++) {
      Ob[(size_t)0 * 768 + d * 16] = f2bf(O[d][0] * inv0);
      Ob[(size_t)1 * 768 + d * 16] = f2bf(O[d][1] * inv1);
      Ob[(size_t)2 * 768 + d * 16] = f2bf(O[d][2] * inv2);
      Ob[(size_t)3 * 768 + d * 16] = f2bf(O[d][3] * inv3);
    }
  } else {
    float m0 = __shfl(m_i, quad * 20 + 0, 64);
    float m1 = __shfl(m_i, quad * 20 + 1, 64);
    float m2 = __shfl(m_i, quad * 20 + 2, 64);
    float m3 = __shfl(m_i, quad * 20 + 3, 64);
    u16* Pb = Part + ((size_t)(bh * 4 + qt) * nsplit + split) * 4096;
    int rowb = w * 16 + quad * 4;
#pragma unroll
    for (int d = 0; d < 4; d++) {
      Pb[(rowb + 0) * 64 + d * 16 + l15] = f2bf(O[d][0]);
      Pb[(rowb + 1) * 64 + d * 16 + l15] = f2bf(O[d][1]);
      Pb[(rowb + 2) * 64 + d * 16 + l15] = f2bf(O[d][2]);
      Pb[(rowb + 3) * 64 + d * 16 + l15] = f2bf(O[d][3]);
    }
    if (l15 == 0) {
      float* MlB = Ml + ((size_t)(bh * 4 + qt) * nsplit + split) * 128;
      MlB[rowb + 0] = m0; MlB[rowb + 1] = m1; MlB[rowb + 2] = m2; MlB[rowb + 3] = m3;
      MlB[64 + rowb + 0] = l0; MlB[64 + rowb + 1] = l1;
      MlB[64 + rowb + 2] = l2; MlB[64 + rowb + 3] = l3;
    }
  }
}

// ---------------- split-KV reduce ----------------
__global__ __launch_bounds__(256) void freduce_kernel(
    const u16* __restrict__ Part, const float* __restrict__ Ml,
    u16* __restrict__ Out, int nsplit) {
  int bid = blockIdx.x;
  int qt = bid & 3, bh = bid >> 2;
  int h = bh % 12, b = bh / 12;
  int tid = threadIdx.x;
  int r = tid >> 2, dc = tid & 3;
  const float* mlb = Ml + (size_t)(bh * 4 + qt) * nsplit * 128;
  float M = -1e30f;
  for (int s = 0; s < nsplit; s++) M = fmaxf(M, mlb[s * 128 + r]);
  float L = 0.f;
  float accv[16];
#pragma unroll
  for (int i = 0; i < 16; i++) accv[i] = 0.f;
  const u16* pb = Part + (size_t)(bh * 4 + qt) * nsplit * 4096 + r * 64 + dc * 16;
  for (int s = 0; s < nsplit; s++) {
    float wgt = __expf(mlb[s * 128 + r] - M);
    L += wgt * mlb[s * 128 + 64 + r];
    u16 tmp[16];
    *(uint4*)tmp = *(const uint4*)(pb + s * 4096);
    *(uint4*)(tmp + 8) = *(const uint4*)(pb + s * 4096 + 8);
#pragma unroll
    for (int i = 0; i < 16; i++) accv[i] += wgt * bf2f(tmp[i]);
  }
  float inv = 1.f / L;
  unsigned ot[8];
#pragma unroll
  for (int i = 0; i < 8; i++)
    ot[i] = pk2bf(accv[2 * i] * inv, accv[2 * i + 1] * inv);
  u16* ob = Out + ((size_t)(b * 256 + qt * 64 + r)) * 768 + h * 64 + dc * 16;
  *(uint4*)ob = *(uint4*)ot;
  *(uint4*)(ob + 8) = *(uint4*)(ot + 4);
}

// ---------------- LayerNorm (fallback path only) ----------------
__global__ __launch_bounds__(256) void ln_kernel(const float* __restrict__ X,
                                                 const float* __restrict__ sc,
                                                 const float* __restrict__ bi,
                                                 u16* __restrict__ Hout) {
  int row = blockIdx.x;
  int tid = threadIdx.x;
  const float* x = X + (size_t)row * 768;
  float v0 = x[tid], v1 = x[tid + 256], v2 = x[tid + 512];
  float s = v0 + v1 + v2;
  float q = v0 * v0 + v1 * v1 + v2 * v2;
#pragma unroll
  for (int m = 1; m < 64; m <<= 1) {
    s += __shfl_xor(s, m, 64);
    q += __shfl_xor(q, m, 64);
  }
  __shared__ float rs[4], rq[4];
  if ((tid & 63) == 0) { rs[tid >> 6] = s; rq[tid >> 6] = q; }
  __syncthreads();
  s = rs[0] + rs[1] + rs[2] + rs[3];
  q = rq[0] + rq[1] + rq[2] + rq[3];
  float mu = s * (1.f / 768.f);
  float var = q * (1.f / 768.f) - mu * mu;
  float rstd = rsqrtf(var + 1e-5f);
  u16* ho = Hout + (size_t)row * 768;
  ho[tid]       = f2bf((v0 - mu) * rstd * sc[tid]       + bi[tid]);
  ho[tid + 256] = f2bf((v1 - mu) * rstd * sc[tid + 256] + bi[tid + 256]);
  ho[tid + 512] = f2bf((v2 - mu) * rstd * sc[tid + 512] + bi[tid + 512]);
}

__global__ __launch_bounds__(256) void copy4_kernel(const float* __restrict__ src,
                                                    float* __restrict__ dst, int n4) {
  int i = blockIdx.x * 256 + threadIdx.x;
  if (i < n4) ((float4*)dst)[i] = ((const float4*)src)[i];
}

// =====================================================================
extern "C" void kernel_launch(void* const* d_in, const int* in_sizes, int n_in,
                              void* d_out, int out_size, void* d_ws, size_t ws_size,
                              hipStream_t stream) {
  const float* pc        = (const float*)d_in[0];
  const float* feats     = (const float*)d_in[1];
  const float* query     = (const float*)d_in[2];
  const float* in_W      = (const float*)d_in[3];
  const float* in_b      = (const float*)d_in[4];
  const float* ca_qkv_W  = (const float*)d_in[5];
  const float* ca_qkv_b  = (const float*)d_in[6];
  const float* ca_proj_W = (const float*)d_in[7];
  const float* ca_proj_b = (const float*)d_in[8];
  const float* ln1_s     = (const float*)d_in[9];
  const float* ln1_b     = (const float*)d_in[10];
  const float* qkv_W     = (const float*)d_in[11];
  const float* qkv_b     = (const float*)d_in[12];
  const float* proj_W    = (const float*)d_in[13];
  const float* proj_b    = (const float*)d_in[14];
  const float* ln2_s     = (const float*)d_in[15];
  const float* ln2_b     = (const float*)d_in[16];
  const float* fc_W      = (const float*)d_in[17];
  const float* fc_b      = (const float*)d_in[18];
  const float* fc2_W     = (const float*)d_in[19];
  const float* fc2_b     = (const float*)d_in[20];

  char* base = (char*)d_ws;
  size_t off = 0;
  auto alloc = [&](size_t bytes) -> char* {
    char* p = base + off;
    off += (bytes + 255) & ~(size_t)255;
    return p;
  };

  // ---- fixed region ----
  u16* WqT     = (u16*)alloc(64 * 768 * 2);
  u16* Wquery  = (u16*)alloc(256 * 768 * 2);
  u16* Wcaqkv  = (u16*)alloc(2304 * 768 * 2);
  u16* Wcaproj = (u16*)alloc(768 * 768 * 2);
  u16* Wkp     = (u16*)alloc(1536 * 64 * 2);
  float* bprime = (float*)alloc(1536 * 4);
  u16* qc      = (u16*)alloc(256 * 768 * 2);
  u16* attn    = (u16*)alloc((size_t)2048 * 768 * 2);
  u16* hbuf    = (u16*)alloc((size_t)2048 * 768 * 2);
  char* uni    = alloc(13369344);
  u16* qkvb    = (u16*)uni;
  u16* VtS     = (u16*)(uni + 9437184);
  u16* fc1     = (u16*)uni;
  u16* Part    = (u16*)uni;
  float* Ml    = (float*)(uni + 12582912);

  size_t fixed_end = off;
  const size_t wAllSz = (size_t)8 * (2304 * 768 + 768 * 768 + 2 * 3072 * 768) * 2;
  auto crossSz = [](int cb) {
    return (size_t)cb * 4096 * 64 * 2 + 2 * ((size_t)cb * 4096 * 768 * 2);
  };

  bool allw; int CB;
  if (fixed_end + (wAllSz > crossSz(8) ? wAllSz : crossSz(8)) + 65536 <= ws_size) {
    allw = true;  CB = 8;
  } else if (fixed_end + 14155776 + crossSz(2) + 65536 <= ws_size) {
    allw = false; CB = 2;
  } else {
    allw = false; CB = 1;
  }

  u16 *WqkvB, *WprojB, *WfcB, *Wfc2B, *emb, *kvbK, *VtC;
  if (allw) {
    char* X = base + off;
    WqkvB  = (u16*)X;
    WprojB = WqkvB + (size_t)8 * 2304 * 768;
    WfcB   = WprojB + (size_t)8 * 768 * 768;
    Wfc2B  = WfcB + (size_t)8 * 3072 * 768;
    emb  = (u16*)X;
    kvbK = (u16*)(X + (size_t)CB * 4096 * 64 * 2);
    VtC  = (u16*)(X + (size_t)CB * 4096 * 64 * 2 + (size_t)CB * 4096 * 768 * 2);
    off = fixed_end + (wAllSz > crossSz(8) ? wAllSz : crossSz(8));
  } else {
    WqkvB  = (u16*)alloc(2304 * 768 * 2);
    WprojB = (u16*)alloc(768 * 768 * 2);
    WfcB   = (u16*)alloc(3072 * 768 * 2);
    Wfc2B  = (u16*)alloc((size_t)768 * 3072 * 2);
    emb  = (u16*)alloc((size_t)CB * 4096 * 64 * 2);
    kvbK = (u16*)alloc((size_t)CB * 4096 * 768 * 2);
    VtC  = (u16*)alloc((size_t)CB * 4096 * 768 * 2);
  }

  // ---- split-K partial buffer (adaptive: degrade if workspace is tight) ----
  const size_t pb2048 = (size_t)2048 * 768 * 4;   // one split of a 2048x768 f32 partial
  auto fits = [&](size_t bytes) { return off + bytes + 4096 <= ws_size; };
  int nsk_fc2 = fits(4 * pb2048) ? 4 : (fits(2 * pb2048) ? 2 : 1);
  int nsk_pr  = fits(2 * pb2048) ? 2 : 1;
  int nsk_qc  = fits((size_t)256 * 768 * 4 * 8) ? 8 : 1;
  float* skP  = (float*)(base + off);   // not bump-allocated; transient reuse
  const bool fuse = (nsk_pr > 1) && (nsk_fc2 > 1);   // LN fused into skredln

  float* latents = (float*)d_out;
  const float scale2 = 0.125f;

  // --- upfront conversions + fused-weight precompute ---
  {
    int n0 = 256 * 768 / 4, n1 = 2304 * 768 / 4, n2 = 768 * 768 / 4;
    cvt4_kernel<<<(n0 + n1 + n2 + 255) / 256, 256, 0, stream>>>(
        query, Wquery, n0, ca_qkv_W, Wcaqkv, n1, ca_proj_W, Wcaproj, n2,
        nullptr, nullptr, 0);
  }
  pad_inwT_kernel<<<192, 256, 0, stream>>>(in_W, WqT);
  gemm_t<64, 64, 2, 2, 0><<<dim3(24, 1), 256, 0, stream>>>(
      Wcaqkv + (size_t)768 * 768, WqT, nullptr, nullptr, nullptr, Wkp,
      1536, 64, 64, 768, 0, nullptr, 0, 0, 0);
  bprime_kernel<<<384, 256, 0, stream>>>(ca_qkv_W, ca_qkv_b, in_b, bprime);

  // --- latent q projection (split-K: 48 blocks -> 384) ---
  if (nsk_qc > 1) {
    gemmsk_t<64, 64, 2, 2><<<dim3(4, 12, nsk_qc), 256, 0, stream>>>(
        Wquery, Wcaqkv, skP, 256, 768, 768, 768 / nsk_qc);
    skred_kernel<<<192, 256, 0, stream>>>(
        skP, nsk_qc, 256 * 768 / 4, 768, ca_qkv_b, nullptr, nullptr, qc);
  } else {
    gemm_t<64, 64, 2, 2, 0><<<dim3(4, 12), 256, 0, stream>>>(
        Wquery, Wcaqkv, ca_qkv_b, nullptr, nullptr, qc,
        256, 768, 768, 768, 0, nullptr, 0, 0, 0);
  }

  // --- cross-attention, chunked over batches ---
  int nchunk = 8 / CB;
  for (int c = 0; c < nchunk; ++c) {
    int Mc = CB * 4096;
    const float* pc_c = pc + (size_t)c * Mc * 3;
    const float* ft_c = feats + (size_t)c * Mc * 3;
    embed_kernel<<<Mc / 4, 256, 0, stream>>>(pc_c, ft_c, emb);
    gemm_t<128, 128, 2, 2, 1><<<dim3(Mc / 128, 12), 256, 0, stream>>>(
        emb, Wkp, bprime, nullptr, nullptr, kvbK,
        Mc, 1536, 768, 64, 0, VtC, 6, 4096, 12);
    flash_kernel<<<CB * 12 * 16, 256, 0, stream>>>(
        qc, 0L, 768, 64, kvbK, (long)4096 * 768, 768, 64, VtC,
        nullptr, Part, Ml, 4096, 4, 1024, CB * 12, scale2);
    freduce_kernel<<<CB * 48, 256, 0, stream>>>(
        Part, Ml, attn + (size_t)c * CB * 256 * 768, 4);
  }
  // cross-proj (+ fused ln1 of layer 0 when fuse)
  if (nsk_pr > 1) {
    gemmsk_t<64, 64, 2, 2><<<dim3(32, 12, nsk_pr), 256, 0, stream>>>(
        attn, Wcaproj, skP, 2048, 768, 768, 768 / nsk_pr);
    if (fuse) {
      skredln_kernel<<<2048, 256, 0, stream>>>(
          skP, nsk_pr, 2048 * 768, ca_proj_b, nullptr,
          ln1_s, ln1_b, latents, hbuf);
    } else {
      skred_kernel<<<1536, 256, 0, stream>>>(
          skP, nsk_pr, 2048 * 768 / 4, 768, ca_proj_b, nullptr, latents, nullptr);
    }
  } else {
    gemm_t<64, 64, 2, 2, 0><<<dim3(32, 12), 256, 0, stream>>>(
        attn, Wcaproj, ca_proj_b, nullptr, latents, nullptr,
        2048, 768, 768, 768, 0, nullptr, 0, 0, 0);
  }

  // --- all-layer weight conversion (one sweep) ---
  if (allw) {
    int n0 = 8 * 2304 * 768 / 4, n1 = 8 * 768 * 768 / 4, n2 = 8 * 3072 * 768 / 4;
    cvt4_kernel<<<(n0 + n1 + 2 * n2 + 255) / 256, 256, 0, stream>>>(
        qkv_W, WqkvB, n0, proj_W, WprojB, n1, fc_W, WfcB, n2, fc2_W, Wfc2B, n2);
  }

  // --- transformer layers ---
  for (int l = 0; l < 8; ++l) {
    u16* Wlq  = allw ? WqkvB  + (size_t)l * 2304 * 768 : WqkvB;
    u16* Wlp  = allw ? WprojB + (size_t)l * 768 * 768  : WprojB;
    u16* Wlf  = allw ? WfcB   + (size_t)l * 3072 * 768 : WfcB;
    u16* Wlf2 = allw ? Wfc2B  + (size_t)l * 3072 * 768 : Wfc2B;
    if (!allw) {
      int n0 = 2304 * 768 / 4, n1 = 768 * 768 / 4, n2 = 3072 * 768 / 4;
      cvt4_kernel<<<(n0 + n1 + 2 * n2 + 255) / 256, 256, 0, stream>>>(
          qkv_W + (size_t)l * 2304 * 768, Wlq, n0,
          proj_W + (size_t)l * 768 * 768, Wlp, n1,
          fc_W + (size_t)l * 3072 * 768, Wlf, n2,
          fc2_W + (size_t)l * 768 * 3072, Wlf2, n2);
    }
    // ln1: fused into the previous skredln when fuse; standalone otherwise
    if (!fuse)
      ln_kernel<<<2048, 256, 0, stream>>>(latents, ln1_s + l * 768, ln1_b + l * 768, hbuf);
    // qkv GEMM with fused V^T write (tiles y%3==2 go straight to VtS)
    gemm_t<64, 64, 2, 2, 2><<<dim3(32, 36), 256, 0, stream>>>(
        hbuf, Wlq, qkv_b + l * 2304, nullptr, nullptr, qkvb,
        2048, 2304, 2304, 768, 0, VtS, 0, 256, 8);
    flash_kernel<<<384, 256, 0, stream>>>(
        qkvb, (long)256 * 2304, 2304, 192, qkvb + 64, (long)256 * 2304, 2304, 192,
        VtS, attn, nullptr, nullptr, 256, 1, 256, 96, scale2);
    // proj (+resid) via split-K; fused ln2 when fuse
    if (nsk_pr > 1) {
      gemmsk_t<64, 64, 2, 2><<<dim3(32, 12, nsk_pr), 256, 0, stream>>>(
          attn, Wlp, skP, 2048, 768, 768, 768 / nsk_pr);
      if (fuse) {
        skredln_kernel<<<2048, 256, 0, stream>>>(
            skP, nsk_pr, 2048 * 768, proj_b + l * 768, latents,
            ln2_s + l * 768, ln2_b + l * 768, latents, hbuf);
      } else {
        skred_kernel<<<1536, 256, 0, stream>>>(
            skP, nsk_pr, 2048 * 768 / 4, 768, proj_b + l * 768, latents, latents, nullptr);
      }
    } else {
      gemm_t<64, 64, 2, 2, 0><<<dim3(32, 12), 256, 0, stream>>>(
          attn, Wlp, proj_b + l * 768, latents, latents, nullptr,
          2048, 768, 768, 768, 0, nullptr, 0, 0, 0);
    }
    if (!fuse)
      ln_kernel<<<2048, 256, 0, stream>>>(latents, ln2_s + l * 768, ln2_b + l * 768, hbuf);
    gemm_t<64, 128, 1, 4, 0><<<dim3(32, 24), 256, 0, stream>>>(
        hbuf, Wlf, fc_b + l * 3072, nullptr, nullptr, fc1,
        2048, 3072, 3072, 768, 1, nullptr, 0, 0, 0);
    // fc2 (+resid) via split-K; fused ln1 of next layer when fuse (none after l=7)
    if (nsk_fc2 > 1) {
      gemmsk_t<64, 64, 2, 2><<<dim3(32, 12, nsk_fc2), 256, 0, stream>>>(
          fc1, Wlf2, skP, 2048, 768, 3072, 3072 / nsk_fc2);
      if (fuse) {
        const float* nsc = (l < 7) ? ln1_s + (l + 1) * 768 : nullptr;
        const float* nbi = (l < 7) ? ln1_b + (l + 1) * 768 : nullptr;
        u16* nho = (l < 7) ? hbuf : nullptr;
        skredln_kernel<<<2048, 256, 0, stream>>>(
            skP, nsk_fc2, 2048 * 768, fc2_b + l * 768, latents,
            nsc, nbi, latents, nho);
      } else {
        skred_kernel<<<1536, 256, 0, stream>>>(
            skP, nsk_fc2, 2048 * 768 / 4, 768, fc2_b + l * 768, latents, latents, nullptr);
      }
    } else {
      gemm_t<64, 64, 2, 2, 0><<<dim3(32, 12), 256, 0, stream>>>(
          fc1, Wlf2, fc2_b + l * 768, latents, latents, nullptr,
          2048, 768, 768, 3072, 0, nullptr, 0, 0, 0);
    }
  }

  // --- second output: pc passthrough ---
  copy4_kernel<<<96, 256, 0, stream>>>(pc, (float*)d_out + (size_t)2048 * 768, 98304 / 4);
}